// Round 4
// baseline (117.329 us; speedup 1.0000x reference)
//
#include <hip/hip_runtime.h>
#include <hip/hip_bf16.h>

// 4-qubit QNN, batch 1M — single fused kernel.
// out[b] = psi^T M psi, psi = prod_i [cos(x_i/2), sin(x_i/2)] (wire i = bit 3-i),
// M = Re(U^dag Z0 U). Per-qubit expansion c^2=(1+C)/2, cs=S/2, s^2=(1-C)/2
// (C=cos x, S=sin x)  =>  out = sum_{g in {1,C,S}^4} K[g] * prod basis.
// Each block rebuilds K in LDS (register+shuffle circuit sim, ~1.5k cy),
// then evaluates the 81-term tensor polynomial, 8 samples/thread as 4x f32x2
// (packed v_pk_fma_f32 path).

typedef float f32x2 __attribute__((ext_vector_type(2)));

#define BLOCK 256
#define NPAIR 4           // 4 f32x2 pairs = 8 samples per thread
#define VEC (2 * NPAIR)

__global__ __launch_bounds__(BLOCK, 4) void qnn_fused_kernel(
    const float4* __restrict__ x, const float* __restrict__ w,
    float* __restrict__ out, int n) {

    __shared__ float Ur[16][17], Ui[16][17];
    __shared__ float Msh[256];
    __shared__ float Ks[81];

    const int t = threadIdx.x;

    // ---- Phase 1: U columns via register+shuffle sim (verified r1) ----
    {
        const int j = t >> 4;   // column (basis input)
        const int k = t & 15;   // row (amplitude index)
        float ur = (k == j) ? 1.0f : 0.0f;
        float ui = 0.0f;

        #pragma unroll
        for (int layer = 0; layer < 2; ++layer) {
            #pragma unroll
            for (int q = 0; q < 4; ++q) {
                const int bit = 3 - q;      // wire q acts on bit (3-q)
                const int str = 1 << bit;
                const int kb = (k >> bit) & 1;
                float c, s, pr, pi, nr, ni;
                // RX
                __sincosf(w[(layer * 4 + q) * 3 + 0] * 0.5f, &s, &c);
                pr = __shfl_xor(ur, str);
                pi = __shfl_xor(ui, str);
                nr = c * ur + s * pi;
                ni = c * ui - s * pr;
                ur = nr; ui = ni;
                // RY
                __sincosf(w[(layer * 4 + q) * 3 + 1] * 0.5f, &s, &c);
                pr = __shfl_xor(ur, str);
                pi = __shfl_xor(ui, str);
                {
                    const float sg = kb ? s : -s;
                    nr = c * ur + sg * pr;
                    ni = c * ui + sg * pi;
                }
                ur = nr; ui = ni;
                // RZ
                __sincosf(w[(layer * 4 + q) * 3 + 2] * 0.5f, &s, &c);
                {
                    const float sz = kb ? s : -s;
                    nr = c * ur - sz * ui;
                    ni = c * ui + sz * ur;
                }
                ur = nr; ui = ni;
            }
            // CNOT ring (0,1),(1,2),(2,3),(3,0)
            #pragma unroll
            for (int g = 0; g < 4; ++g) {
                const int cw = g;
                const int tw = (g + 1) & 3;
                const int bc = 3 - cw, bt = 3 - tw;
                const float pr = __shfl_xor(ur, 1 << bt);
                const float pi = __shfl_xor(ui, 1 << bt);
                const bool ctl = (k >> bc) & 1;
                ur = ctl ? pr : ur;
                ui = ctl ? pi : ui;
            }
        }
        Ur[k][j] = ur;
        Ui[k][j] = ui;
    }
    __syncthreads();

    // ---- Phase 2: M[a][b] = sum_k z_k Re(conj(U[k][a]) U[k][b]) ----
    {
        const int a = t >> 4, b = t & 15;
        float acc = 0.0f;
        #pragma unroll
        for (int kk = 0; kk < 16; ++kk) {
            const float v2 = Ur[kk][a] * Ur[kk][b] + Ui[kk][a] * Ui[kk][b];
            acc += (kk & 8) ? -v2 : v2;
        }
        Msh[t] = acc;
    }
    __syncthreads();

    // ---- Phase 3: 81 tensor coefficients ----
    if (t < 81) {
        const int d0 = t / 27, d1 = (t / 9) % 3, d2 = (t / 3) % 3, d3 = t % 3;
        const int gd[4] = {d3, d2, d1, d0};  // digit per bit p
        float sum = 0.0f;
        #pragma unroll
        for (int m = 0; m < 16; ++m) {
            int a2 = 0, b2 = 0;
            float sign = 1.0f;
            #pragma unroll
            for (int p = 0; p < 4; ++p) {
                const int cp = (m >> p) & 1;
                if (gd[p] == 2) { a2 |= cp << p; b2 |= (1 - cp) << p; }
                else {
                    a2 |= cp << p; b2 |= cp << p;
                    if (gd[p] == 1 && cp) sign = -sign;
                }
            }
            sum += sign * Msh[a2 * 16 + b2];
        }
        Ks[t] = sum * 0.0625f;
    }
    __syncthreads();

    // ---- Phase 4: eval, 8 samples/thread as 4 packed pairs ----
    const int gid = blockIdx.x * BLOCK + t;
    const int stride = gridDim.x * BLOCK;

    for (int i0 = gid; i0 < n; i0 += stride * VEC) {
        int idxA[NPAIR], idxB[NPAIR];
        bool okA[NPAIR], okB[NPAIR];
        f32x2 C2[NPAIR][4], S2[NPAIR][4];

        #pragma unroll
        for (int u = 0; u < NPAIR; ++u) {
            {   // sample 2u -> lane .x
                const int ii = i0 + (2 * u) * stride;
                okA[u] = ii < n;
                idxA[u] = okA[u] ? ii : (n - 1);
                const float4 xv = x[idxA[u]];
                float s, c;
                __sincosf(xv.x, &s, &c); C2[u][0].x = c; S2[u][0].x = s;
                __sincosf(xv.y, &s, &c); C2[u][1].x = c; S2[u][1].x = s;
                __sincosf(xv.z, &s, &c); C2[u][2].x = c; S2[u][2].x = s;
                __sincosf(xv.w, &s, &c); C2[u][3].x = c; S2[u][3].x = s;
            }
            {   // sample 2u+1 -> lane .y
                const int ii = i0 + (2 * u + 1) * stride;
                okB[u] = ii < n;
                idxB[u] = okB[u] ? ii : (n - 1);
                const float4 xv = x[idxB[u]];
                float s, c;
                __sincosf(xv.x, &s, &c); C2[u][0].y = c; S2[u][0].y = s;
                __sincosf(xv.y, &s, &c); C2[u][1].y = c; S2[u][1].y = s;
                __sincosf(xv.z, &s, &c); C2[u][2].y = c; S2[u][2].y = s;
                __sincosf(xv.w, &s, &c); C2[u][3].y = c; S2[u][3].y = s;
            }
        }

        f32x2 r[NPAIR];
        #pragma unroll
        for (int d0 = 0; d0 < 3; ++d0) {
            f32x2 a1[NPAIR];
            #pragma unroll
            for (int d1 = 0; d1 < 3; ++d1) {
                f32x2 a2[NPAIR];
                #pragma unroll
                for (int d2 = 0; d2 < 3; ++d2) {
                    const int base = ((d0 * 3 + d1) * 3 + d2) * 3;
                    const float k0 = Ks[base], k1 = Ks[base + 1], k2 = Ks[base + 2];
                    const f32x2 k0v = {k0, k0}, k1v = {k1, k1}, k2v = {k2, k2};
                    #pragma unroll
                    for (int u = 0; u < NPAIR; ++u) {
                        const f32x2 tt = __builtin_elementwise_fma(
                            k2v, S2[u][3],
                            __builtin_elementwise_fma(k1v, C2[u][3], k0v));
                        if (d2 == 0) a2[u] = tt;
                        else a2[u] = __builtin_elementwise_fma(
                                 tt, (d2 == 1) ? C2[u][2] : S2[u][2], a2[u]);
                    }
                }
                #pragma unroll
                for (int u = 0; u < NPAIR; ++u) {
                    if (d1 == 0) a1[u] = a2[u];
                    else a1[u] = __builtin_elementwise_fma(
                             a2[u], (d1 == 1) ? C2[u][1] : S2[u][1], a1[u]);
                }
            }
            #pragma unroll
            for (int u = 0; u < NPAIR; ++u) {
                if (d0 == 0) r[u] = a1[u];
                else r[u] = __builtin_elementwise_fma(
                         a1[u], (d0 == 1) ? C2[u][0] : S2[u][0], r[u]);
            }
        }

        #pragma unroll
        for (int u = 0; u < NPAIR; ++u) {
            if (okA[u]) out[idxA[u]] = r[u].x;
            if (okB[u]) out[idxB[u]] = r[u].y;
        }
    }
}

// ---------------- launch ----------------
extern "C" void kernel_launch(void* const* d_in, const int* in_sizes, int n_in,
                              void* d_out, int out_size, void* d_ws, size_t ws_size,
                              hipStream_t stream) {
    const float* x = (const float*)d_in[0];
    const float* w = (const float*)d_in[1];
    float* out = (float*)d_out;

    const int n = in_sizes[0] / 4;  // batch

    int grid = (n + BLOCK * VEC - 1) / (BLOCK * VEC);  // 512 for n = 1M
    if (grid < 1) grid = 1;
    if (grid > 2048) grid = 2048;

    qnn_fused_kernel<<<grid, BLOCK, 0, stream>>>((const float4*)x, w, out, n);
}

// Round 5
// 70.391 us; speedup vs baseline: 1.6668x; 1.6668x over previous
//
#include <hip/hip_runtime.h>
#include <hip/hip_bf16.h>

// 4-qubit QNN, batch 1M — single fused kernel, spill-free.
// out[b] = psi^T M psi, psi = prod_i [cos(x_i/2), sin(x_i/2)] (wire i = bit 3-i),
// M = Re(U^dag Z0 U). Per-qubit expansion c^2=(1+C)/2, cs=S/2, s^2=(1-C)/2
// (C=cos x, S=sin x)  =>  out = sum_{g in {1,C,S}^4} K[g] * prod basis.
// Each block rebuilds the 81 coefficients K in LDS (register+shuffle circuit
// sim), hoists them to SGPRs via readfirstlane (wave-uniform), then streams
// samples: scalar Horner, 80 FMA/sample with SGPR coefficient operands.

#define BLOCK 256
#define VEC 4   // samples per thread

__global__ __launch_bounds__(BLOCK, 4) void qnn_fused_kernel(
    const float4* __restrict__ x, const float* __restrict__ w,
    float* __restrict__ out, int n) {

    __shared__ float Ur[16][17], Ui[16][17];
    __shared__ float Msh[256];
    __shared__ float Ks[81];

    const int t = threadIdx.x;

    // ---- Phase 1: U columns via register+shuffle sim (verified r1/r3) ----
    {
        const int j = t >> 4;   // column (basis input)
        const int k = t & 15;   // row (amplitude index)
        float ur = (k == j) ? 1.0f : 0.0f;
        float ui = 0.0f;

        #pragma unroll
        for (int layer = 0; layer < 2; ++layer) {
            #pragma unroll
            for (int q = 0; q < 4; ++q) {
                const int bit = 3 - q;      // wire q acts on bit (3-q)
                const int str = 1 << bit;
                const int kb = (k >> bit) & 1;
                float c, s, pr, pi, nr, ni;
                // RX
                __sincosf(w[(layer * 4 + q) * 3 + 0] * 0.5f, &s, &c);
                pr = __shfl_xor(ur, str);
                pi = __shfl_xor(ui, str);
                nr = c * ur + s * pi;
                ni = c * ui - s * pr;
                ur = nr; ui = ni;
                // RY
                __sincosf(w[(layer * 4 + q) * 3 + 1] * 0.5f, &s, &c);
                pr = __shfl_xor(ur, str);
                pi = __shfl_xor(ui, str);
                {
                    const float sg = kb ? s : -s;
                    nr = c * ur + sg * pr;
                    ni = c * ui + sg * pi;
                }
                ur = nr; ui = ni;
                // RZ
                __sincosf(w[(layer * 4 + q) * 3 + 2] * 0.5f, &s, &c);
                {
                    const float sz = kb ? s : -s;
                    nr = c * ur - sz * ui;
                    ni = c * ui + sz * ur;
                }
                ur = nr; ui = ni;
            }
            // CNOT ring (0,1),(1,2),(2,3),(3,0)
            #pragma unroll
            for (int g = 0; g < 4; ++g) {
                const int cw = g;
                const int tw = (g + 1) & 3;
                const int bc = 3 - cw, bt = 3 - tw;
                const float pr = __shfl_xor(ur, 1 << bt);
                const float pi = __shfl_xor(ui, 1 << bt);
                const bool ctl = (k >> bc) & 1;
                ur = ctl ? pr : ur;
                ui = ctl ? pi : ui;
            }
        }
        Ur[k][j] = ur;
        Ui[k][j] = ui;
    }
    __syncthreads();

    // ---- Phase 2: M[a][b] = sum_k z_k Re(conj(U[k][a]) U[k][b]) ----
    {
        const int a = t >> 4, b = t & 15;
        float acc = 0.0f;
        #pragma unroll
        for (int kk = 0; kk < 16; ++kk) {
            const float v2 = Ur[kk][a] * Ur[kk][b] + Ui[kk][a] * Ui[kk][b];
            acc += (kk & 8) ? -v2 : v2;
        }
        Msh[t] = acc;
    }
    __syncthreads();

    // ---- Phase 3: 81 tensor coefficients ----
    if (t < 81) {
        const int d0 = t / 27, d1 = (t / 9) % 3, d2 = (t / 3) % 3, d3 = t % 3;
        const int gd[4] = {d3, d2, d1, d0};  // digit per bit p
        float sum = 0.0f;
        #pragma unroll
        for (int m = 0; m < 16; ++m) {
            int a2 = 0, b2 = 0;
            float sign = 1.0f;
            #pragma unroll
            for (int p = 0; p < 4; ++p) {
                const int cp = (m >> p) & 1;
                if (gd[p] == 2) { a2 |= cp << p; b2 |= (1 - cp) << p; }
                else {
                    a2 |= cp << p; b2 |= cp << p;
                    if (gd[p] == 1 && cp) sign = -sign;
                }
            }
            sum += sign * Msh[a2 * 16 + b2];
        }
        Ks[t] = sum * 0.0625f;
    }
    __syncthreads();

    // ---- Hoist K to wave-uniform (SGPR) values: one LDS read each, ever ----
    float kk[81];
    #pragma unroll
    for (int i = 0; i < 81; ++i)
        kk[i] = __uint_as_float(
            (unsigned)__builtin_amdgcn_readfirstlane(__float_as_uint(Ks[i])));

    // ---- Phase 4: stream samples, scalar Horner (80 FMA/sample) ----
    const int gid = blockIdx.x * BLOCK + t;
    const int stride = gridDim.x * BLOCK;

    for (int i0 = gid; i0 < n; i0 += stride * VEC) {
        int idx[VEC];
        bool ok[VEC];
        float4 xv[VEC];
        #pragma unroll
        for (int v = 0; v < VEC; ++v) {      // cluster the global loads
            const int ii = i0 + v * stride;
            ok[v] = ii < n;
            idx[v] = ok[v] ? ii : (n - 1);
            xv[v] = x[idx[v]];
        }

        #pragma unroll
        for (int v = 0; v < VEC; ++v) {      // then compute one sample at a time
            float C[4], S[4];
            __sincosf(xv[v].x, &S[0], &C[0]);
            __sincosf(xv[v].y, &S[1], &C[1]);
            __sincosf(xv[v].z, &S[2], &C[2]);
            __sincosf(xv[v].w, &S[3], &C[3]);

            float r = 0.0f;
            #pragma unroll
            for (int d0 = 0; d0 < 3; ++d0) {
                float a1 = 0.0f;
                #pragma unroll
                for (int d1 = 0; d1 < 3; ++d1) {
                    float a2 = 0.0f;
                    #pragma unroll
                    for (int d2 = 0; d2 < 3; ++d2) {
                        const int base = ((d0 * 3 + d1) * 3 + d2) * 3;
                        const float tt = fmaf(kk[base + 2], S[3],
                                         fmaf(kk[base + 1], C[3], kk[base]));
                        if (d2 == 0) a2 = tt;
                        else a2 = fmaf(tt, (d2 == 1) ? C[2] : S[2], a2);
                    }
                    if (d1 == 0) a1 = a2;
                    else a1 = fmaf(a2, (d1 == 1) ? C[1] : S[1], a1);
                }
                if (d0 == 0) r = a1;
                else r = fmaf(a1, (d0 == 1) ? C[0] : S[0], r);
            }
            if (ok[v]) out[idx[v]] = r;
        }
    }
}

// ---------------- launch ----------------
extern "C" void kernel_launch(void* const* d_in, const int* in_sizes, int n_in,
                              void* d_out, int out_size, void* d_ws, size_t ws_size,
                              hipStream_t stream) {
    const float* x = (const float*)d_in[0];
    const float* w = (const float*)d_in[1];
    float* out = (float*)d_out;

    const int n = in_sizes[0] / 4;  // batch

    int grid = (n + BLOCK * VEC - 1) / (BLOCK * VEC);  // 1024 for n = 1M
    if (grid < 1) grid = 1;
    if (grid > 4096) grid = 4096;

    qnn_fused_kernel<<<grid, BLOCK, 0, stream>>>((const float4*)x, w, out, n);
}

// Round 6
// 69.874 us; speedup vs baseline: 1.6791x; 1.0074x over previous
//
#include <hip/hip_runtime.h>
#include <hip/hip_bf16.h>

// 4-qubit QNN, batch 1M — single fused kernel, no spill, LDS-broadcast K.
// out[b] = psi^T M psi, psi = prod_i [cos(x_i/2), sin(x_i/2)] (wire i = bit 3-i),
// M = Re(U^dag Z0 U). Per-qubit expansion c^2=(1+C)/2, cs=S/2, s^2=(1-C)/2
// (C=cos x, S=sin x)  =>  out = sum_{g in {1,C,S}^4} K[g] * prod basis.
// Each block rebuilds the 81 coefficients K in LDS (register+shuffle circuit
// sim, ~2 us overlapped), then streams samples: scalar Horner, 80 FMA/sample;
// K read from LDS per coefficient-triple, amortized over VEC samples
// (wave-uniform address -> broadcast, conflict-free).

#define BLOCK 256
#define VEC 4   // samples per thread

__global__ __launch_bounds__(BLOCK) void qnn_fused_kernel(
    const float4* __restrict__ x, const float* __restrict__ w,
    float* __restrict__ out, int n) {

    __shared__ float Ur[16][17], Ui[16][17];
    __shared__ float Msh[256];
    __shared__ float Ks[81];

    const int t = threadIdx.x;

    // ---- Phase 1: U columns via register+shuffle sim (verified r1/r3) ----
    {
        const int j = t >> 4;   // column (basis input)
        const int k = t & 15;   // row (amplitude index)
        float ur = (k == j) ? 1.0f : 0.0f;
        float ui = 0.0f;

        #pragma unroll
        for (int layer = 0; layer < 2; ++layer) {
            #pragma unroll
            for (int q = 0; q < 4; ++q) {
                const int bit = 3 - q;      // wire q acts on bit (3-q)
                const int str = 1 << bit;
                const int kb = (k >> bit) & 1;
                float c, s, pr, pi, nr, ni;
                // RX
                __sincosf(w[(layer * 4 + q) * 3 + 0] * 0.5f, &s, &c);
                pr = __shfl_xor(ur, str);
                pi = __shfl_xor(ui, str);
                nr = c * ur + s * pi;
                ni = c * ui - s * pr;
                ur = nr; ui = ni;
                // RY
                __sincosf(w[(layer * 4 + q) * 3 + 1] * 0.5f, &s, &c);
                pr = __shfl_xor(ur, str);
                pi = __shfl_xor(ui, str);
                {
                    const float sg = kb ? s : -s;
                    nr = c * ur + sg * pr;
                    ni = c * ui + sg * pi;
                }
                ur = nr; ui = ni;
                // RZ
                __sincosf(w[(layer * 4 + q) * 3 + 2] * 0.5f, &s, &c);
                {
                    const float sz = kb ? s : -s;
                    nr = c * ur - sz * ui;
                    ni = c * ui + sz * ur;
                }
                ur = nr; ui = ni;
            }
            // CNOT ring (0,1),(1,2),(2,3),(3,0)
            #pragma unroll
            for (int g = 0; g < 4; ++g) {
                const int cw = g;
                const int tw = (g + 1) & 3;
                const int bc = 3 - cw, bt = 3 - tw;
                const float pr = __shfl_xor(ur, 1 << bt);
                const float pi = __shfl_xor(ui, 1 << bt);
                const bool ctl = (k >> bc) & 1;
                ur = ctl ? pr : ur;
                ui = ctl ? pi : ui;
            }
        }
        Ur[k][j] = ur;
        Ui[k][j] = ui;
    }
    __syncthreads();

    // ---- Phase 2: M[a][b] = sum_k z_k Re(conj(U[k][a]) U[k][b]) ----
    {
        const int a = t >> 4, b = t & 15;
        float acc = 0.0f;
        #pragma unroll
        for (int kk = 0; kk < 16; ++kk) {
            const float v2 = Ur[kk][a] * Ur[kk][b] + Ui[kk][a] * Ui[kk][b];
            acc += (kk & 8) ? -v2 : v2;
        }
        Msh[t] = acc;
    }
    __syncthreads();

    // ---- Phase 3: 81 tensor coefficients ----
    if (t < 81) {
        const int d0 = t / 27, d1 = (t / 9) % 3, d2 = (t / 3) % 3, d3 = t % 3;
        const int gd[4] = {d3, d2, d1, d0};  // digit per bit p
        float sum = 0.0f;
        #pragma unroll
        for (int m = 0; m < 16; ++m) {
            int a2 = 0, b2 = 0;
            float sign = 1.0f;
            #pragma unroll
            for (int p = 0; p < 4; ++p) {
                const int cp = (m >> p) & 1;
                if (gd[p] == 2) { a2 |= cp << p; b2 |= (1 - cp) << p; }
                else {
                    a2 |= cp << p; b2 |= cp << p;
                    if (gd[p] == 1 && cp) sign = -sign;
                }
            }
            sum += sign * Msh[a2 * 16 + b2];
        }
        Ks[t] = sum * 0.0625f;
    }
    __syncthreads();

    // ---- Phase 4: stream samples, scalar Horner (80 FMA/sample) ----
    // K stays in LDS; each coefficient is read ONCE per VEC-group per thread
    // (wave-uniform address -> broadcast), reused across VEC samples.
    const int gid = blockIdx.x * BLOCK + t;
    const int stride = gridDim.x * BLOCK;

    for (int i0 = gid; i0 < n; i0 += stride * VEC) {
        int idx[VEC];
        bool ok[VEC];
        float4 xv[VEC];
        #pragma unroll
        for (int v = 0; v < VEC; ++v) {      // cluster the global loads
            const int ii = i0 + v * stride;
            ok[v] = ii < n;
            idx[v] = ok[v] ? ii : (n - 1);
            xv[v] = x[idx[v]];
        }

        float C[VEC][4], S[VEC][4];
        #pragma unroll
        for (int v = 0; v < VEC; ++v) {
            __sincosf(xv[v].x, &S[v][0], &C[v][0]);
            __sincosf(xv[v].y, &S[v][1], &C[v][1]);
            __sincosf(xv[v].z, &S[v][2], &C[v][2]);
            __sincosf(xv[v].w, &S[v][3], &C[v][3]);
        }

        float r[VEC];
        #pragma unroll
        for (int d0 = 0; d0 < 3; ++d0) {
            float a1[VEC];
            #pragma unroll
            for (int d1 = 0; d1 < 3; ++d1) {
                float a2[VEC];
                #pragma unroll
                for (int d2 = 0; d2 < 3; ++d2) {
                    const int base = ((d0 * 3 + d1) * 3 + d2) * 3;
                    const float k0 = Ks[base], k1 = Ks[base + 1], k2 = Ks[base + 2];
                    #pragma unroll
                    for (int v = 0; v < VEC; ++v) {
                        const float tt = fmaf(k2, S[v][3], fmaf(k1, C[v][3], k0));
                        if (d2 == 0) a2[v] = tt;
                        else a2[v] = fmaf(tt, (d2 == 1) ? C[v][2] : S[v][2], a2[v]);
                    }
                }
                #pragma unroll
                for (int v = 0; v < VEC; ++v) {
                    if (d1 == 0) a1[v] = a2[v];
                    else a1[v] = fmaf(a2[v], (d1 == 1) ? C[v][1] : S[v][1], a1[v]);
                }
            }
            #pragma unroll
            for (int v = 0; v < VEC; ++v) {
                if (d0 == 0) r[v] = a1[v];
                else r[v] = fmaf(a1[v], (d0 == 1) ? C[v][0] : S[v][0], r[v]);
            }
        }

        #pragma unroll
        for (int v = 0; v < VEC; ++v)
            if (ok[v]) out[idx[v]] = r[v];
    }
}

// ---------------- launch ----------------
extern "C" void kernel_launch(void* const* d_in, const int* in_sizes, int n_in,
                              void* d_out, int out_size, void* d_ws, size_t ws_size,
                              hipStream_t stream) {
    const float* x = (const float*)d_in[0];
    const float* w = (const float*)d_in[1];
    float* out = (float*)d_out;

    const int n = in_sizes[0] / 4;  // batch

    int grid = (n + BLOCK * VEC - 1) / (BLOCK * VEC);  // 1024 for n = 1M
    if (grid < 1) grid = 1;
    if (grid > 4096) grid = 4096;

    qnn_fused_kernel<<<grid, BLOCK, 0, stream>>>((const float4*)x, w, out, n);
}